// Round 17
// baseline (994.483 us; speedup 1.0000x reference)
//
#include <hip/hip_runtime.h>
#include <hip/hip_bf16.h>

typedef __hip_bfloat16 bf16;
typedef __attribute__((ext_vector_type(8))) short frag8;   // 8 bf16 = 4 VGPR (MFMA A/B)
typedef __attribute__((ext_vector_type(4))) float f32x4;   // MFMA C/D

#define N0c 331776
#define N1c 36864
#define N2c 4096
#define E0c 294912
#define E1c 32768

// ---------- helpers ----------
__device__ __forceinline__ float bfbits2f(unsigned short b) {
    union { unsigned u; float f; } x; x.u = ((unsigned)b) << 16; return x.f;
}
__device__ __forceinline__ float bfval2f(const bf16* p) {   // bit-correct bf16 -> f32
    return bfbits2f(*reinterpret_cast<const unsigned short*>(p));
}
__device__ __forceinline__ unsigned short f2bfbits(float f) {
    bf16 h = __float2bfloat16(f);
    return *reinterpret_cast<unsigned short*>(&h);
}
__device__ __forceinline__ void load4f(const float* p, float* o) {
    const float4 v = *reinterpret_cast<const float4*>(p);
    o[0] = v.x; o[1] = v.y; o[2] = v.z; o[3] = v.w;
}
__device__ __forceinline__ ushort4 pack4(float4 v) {
    ushort4 o; o.x = f2bfbits(v.x); o.y = f2bfbits(v.y);
    o.z = f2bfbits(v.z); o.w = f2bfbits(v.w); return o;
}
__device__ __forceinline__ void store_c(float* p, float v) { *p = v; }
__device__ __forceinline__ void store_c(bf16* p, float v)  { *p = __float2bfloat16(v); }
__device__ __forceinline__ f32x4 zero4() {
    f32x4 z; z[0] = 0.f; z[1] = 0.f; z[2] = 0.f; z[3] = 0.f; return z;
}
__device__ __forceinline__ f32x4 mfma16(frag8 a, frag8 b, f32x4 c) {
    return __builtin_amdgcn_mfma_f32_16x16x32_bf16(a, b, c, 0, 0, 0);
}

// ---------- prep: fp32 [K][N] -> bf16 transposed [N][K] ----------
__global__ __launch_bounds__(256) void transpose_bf16(
    const float* __restrict__ src, bf16* __restrict__ dst, int K, int N)
{
    const int idx = blockIdx.x * 256 + threadIdx.x;
    if (idx >= K * N) return;
    const int k = idx / N, n = idx - k * N;
    dst[(size_t)n * K + k] = __float2bfloat16(src[idx]);
}

// ---------- CSR build ----------
__global__ __launch_bounds__(256) void hist_kernel(
    const int* __restrict__ dst, const float* __restrict__ w,
    int* __restrict__ cnt, float* __restrict__ wsum, int E)
{
    const int e = blockIdx.x * 256 + threadIdx.x;
    if (e < E) {
        const int d = dst[e];
        atomicAdd(&cnt[d], 1);
        atomicAdd(&wsum[d], w[e]);
    }
}

__global__ __launch_bounds__(256) void invws_kernel(
    const float* __restrict__ wsum, float* __restrict__ invws, int n)
{
    const int i = blockIdx.x * 256 + threadIdx.x;
    if (i < n) invws[i] = 1.f / fmaxf(wsum[i], 1.f);
}

// n multiple of 4096 (chunk stays multiple of 4 for int4 loads)
__global__ __launch_bounds__(1024) void scan_kernel(
    const int* __restrict__ cnt, int* __restrict__ base, int n)
{
    __shared__ int ps[1024];
    const int t = threadIdx.x;
    const int chunk = (n + 1023) >> 10;
    const int lo = t * chunk;
    const int hi = (lo + chunk < n) ? lo + chunk : n;
    int s = 0;
    for (int i = lo; i < hi; i += 4) {
        const int4 v = *reinterpret_cast<const int4*>(cnt + i);
        s += v.x + v.y + v.z + v.w;
    }
    ps[t] = s;
    __syncthreads();
    for (int off = 1; off < 1024; off <<= 1) {
        int v = (t >= off) ? ps[t - off] : 0;
        __syncthreads();
        ps[t] += v;
        __syncthreads();
    }
    int run = ps[t] - s;
    for (int i = lo; i < hi; ++i) { base[i] = run; run += cnt[i]; }
    if (t == 1023) base[n] = ps[1023];
}

__global__ __launch_bounds__(256) void fill_kernel(
    const int* __restrict__ dst, const int* __restrict__ base,
    int* __restrict__ cursor, int* __restrict__ perm, int E)
{
    const int e = blockIdx.x * 256 + threadIdx.x;
    if (e < E) {
        const int d = dst[e];
        const int p = base[d] + atomicAdd(&cursor[d], 1);
        perm[p] = e;
    }
}

// ---------- MFMA proj GEMM: C[M,256] = A[M,128] @ Wp + bp (R7-proven) ----------
template<typename TC>
__global__ __launch_bounds__(256) void gemm_mfma_proj(
    const float* __restrict__ A, const bf16* __restrict__ WpT,
    const float* __restrict__ bp, TC* __restrict__ C)
{
    __shared__ bf16 Xs[64 * 136];

    const int tid = threadIdx.x;
    const int lane = tid & 63, wave = tid >> 6;
    const int row0 = blockIdx.x * 64;

    {   // stage A rows -> bf16 LDS
        const int r = tid >> 2, q = tid & 3;
        const float* ar = A + (size_t)(row0 + r) * 128 + q * 32;
        bf16* xr = Xs + r * 136 + q * 32;
        #pragma unroll
        for (int i = 0; i < 8; ++i)
            *reinterpret_cast<ushort4*>(xr + i * 4) =
                pack4(*reinterpret_cast<const float4*>(ar + i * 4));
    }
    __syncthreads();

    const int lr = lane & 15;
    const int lk = (lane >> 4) * 8;
    const int lm4 = (lane >> 4) * 4;

    f32x4 acc[4][4];
    #pragma unroll
    for (int mi = 0; mi < 4; ++mi)
        #pragma unroll
        for (int ni = 0; ni < 4; ++ni) acc[mi][ni] = zero4();

    #pragma unroll
    for (int kk = 0; kk < 4; ++kk) {
        frag8 a[4], b[4];
        #pragma unroll
        for (int mi = 0; mi < 4; ++mi)
            a[mi] = *reinterpret_cast<const frag8*>(&Xs[(mi * 16 + lr) * 136 + kk * 32 + lk]);
        #pragma unroll
        for (int ni = 0; ni < 4; ++ni)
            b[ni] = *reinterpret_cast<const frag8*>(
                WpT + (size_t)(wave * 64 + ni * 16 + lr) * 128 + kk * 32 + lk);
        #pragma unroll
        for (int mi = 0; mi < 4; ++mi)
            #pragma unroll
            for (int ni = 0; ni < 4; ++ni)
                acc[mi][ni] = mfma16(a[mi], b[ni], acc[mi][ni]);
    }

    #pragma unroll
    for (int ni = 0; ni < 4; ++ni) {
        const int c = wave * 64 + ni * 16 + lr;
        const float bb = bp[c];
        #pragma unroll
        for (int mi = 0; mi < 4; ++mi)
            #pragma unroll
            for (int i = 0; i < 4; ++i)
                store_c(C + (size_t)(row0 + mi * 16 + lm4 + i) * 256 + c,
                        acc[mi][ni][i] + bb);
    }
}

// ---------- wave-synchronous fused edge transform + segment reduce (CSR order) ----------
// ZERO block barriers: each wave owns 16 CSR rows end-to-end (private meta,
// gather, MFMA, Os staging, column scan, atomic flush). Waves slip freely so
// no wave ever waits on another wave's gather/atomic drain (the 5x
// vmcnt(0)-before-s_barrier drains of the barriered version are eliminated).
// Same-wave LDS ordering: in-order DS ops + wave_barrier (compile-time fence).
// All flushes atomicAdd onto zero-init m (order-independent, race-free).
__global__ __launch_bounds__(256) void edge_reduce_wave(
    const bf16* __restrict__ zn, const bf16* __restrict__ QT,
    const float* __restrict__ bq,
    const int* __restrict__ perm, const int* __restrict__ srcv,
    const int* __restrict__ dstv, const float* __restrict__ w,
    const float* __restrict__ invws, float* __restrict__ mout)
{
    __shared__ bf16 Zs[4 * 16 * 264];   // 33.0 KB: per-wave gathered input
    __shared__ bf16 Os[4 * 16 * 136];   // 17.0 KB: per-wave staged outputs (128 cols/pass)
    __shared__ int   sS[64];
    __shared__ int   sD[64];
    __shared__ float sW[64];

    const int tid = threadIdx.x;
    const int lane = tid & 63, wave = tid >> 6;
    const size_t p0 = (size_t)blockIdx.x * 64 + wave * 16;

    bf16*  zw = Zs + wave * (16 * 264);
    bf16*  ow = Os + wave * (16 * 136);
    int*   ss = sS + wave * 16;
    int*   sd = sD + wave * 16;
    float* sw = sW + wave * 16;

    if (lane < 16) {
        const int e = perm[p0 + lane];
        ss[lane] = srcv[e];
        sd[lane] = dstv[e];
        sw[lane] = w[e];
    }
    __builtin_amdgcn_wave_barrier();

    {   // gather 16 rows x 256 bf16: lane -> (row lane>>2, quarter lane&3), 8x16B
        const int r = lane >> 2, q = lane & 3;
        const int4* zr = reinterpret_cast<const int4*>(zn + (size_t)ss[r] * 256 + q * 64);
        int4* zo = reinterpret_cast<int4*>(zw + r * 264 + q * 64);
        #pragma unroll
        for (int i = 0; i < 4; ++i) zo[i] = zr[i];
        #pragma unroll
        for (int i = 4; i < 8; ++i) zo[i] = zr[i];
    }
    __builtin_amdgcn_wave_barrier();

    const int lr = lane & 15;
    const int lk = (lane >> 4) * 8;
    const int lm4 = (lane >> 4) * 4;

    for (int cp = 0; cp < 4; ++cp) {           // 4 col-passes of 128
        const int nc0 = cp * 128;
        f32x4 acc[8];
        #pragma unroll
        for (int ni = 0; ni < 8; ++ni) acc[ni] = zero4();

        #pragma unroll
        for (int kk = 0; kk < 8; ++kk) {
            const frag8 a = *reinterpret_cast<const frag8*>(&zw[lr * 264 + kk * 32 + lk]);
            #pragma unroll
            for (int ni = 0; ni < 8; ++ni) {
                const frag8 b = *reinterpret_cast<const frag8*>(
                    QT + (size_t)(nc0 + ni * 16 + lr) * 256 + kk * 32 + lk);
                acc[ni] = mfma16(a, b, acc[ni]);
            }
        }

        // epilogue: relu+bias, weight by w[row], stage to ow (cols 0..127 of pass)
        #pragma unroll
        for (int ni = 0; ni < 8; ++ni) {
            const int gc = nc0 + ni * 16 + lr;
            const float bb = bq[gc];
            const int lc = ni * 16 + lr;
            #pragma unroll
            for (int i = 0; i < 4; ++i) {
                const int row = lm4 + i;
                const float val = fmaxf(acc[ni][i] + bb, 0.f) * sw[row];
                ow[row * 136 + lc] = __float2bfloat16(val);
            }
        }
        __builtin_amdgcn_wave_barrier();

        // scan: lane owns 2 cols of this pass; scan the wave's 16 CSR-sorted rows
        #pragma unroll
        for (int cidx = 0; cidx < 2; ++cidx) {
            const int lc = lane * 2 + cidx;
            const int gc = nc0 + lc;
            float a = 0.f;
            int cur = sd[0];
            for (int r = 0; r < 16; ++r) {
                const int d = sd[r];
                if (d != cur) {
                    atomicAdd(&mout[(size_t)cur * 512 + gc], a * invws[cur]);
                    a = 0.f; cur = d;
                }
                a += bfval2f(&ow[r * 136 + lc]);   // bit-reinterpret read
            }
            atomicAdd(&mout[(size_t)cur * 512 + gc], a * invws[cur]);
        }
        __builtin_amdgcn_wave_barrier();           // ow reused next pass
    }
}

// ---------- MFMA concat GEMM: C[M,256] = relu([m_f32 | hdst] @ W + bias) ----------
template<typename TC>
__global__ __launch_bounds__(256) void gemm_mfma_concat(
    const float* __restrict__ m, const bf16* __restrict__ hdst,
    const bf16* __restrict__ WT, const float* __restrict__ bias,
    TC* __restrict__ C)
{
    __shared__ bf16 As[64 * 136];

    const int tid = threadIdx.x;
    const int lane = tid & 63, wave = tid >> 6;
    const int row0 = blockIdx.x * 64;
    const int r = tid >> 2, q = tid & 3;

    const int lr = lane & 15;
    const int lk = (lane >> 4) * 8;
    const int lm4 = (lane >> 4) * 4;

    f32x4 acc[4][4];
    #pragma unroll
    for (int mi = 0; mi < 4; ++mi)
        #pragma unroll
        for (int ni = 0; ni < 4; ++ni) acc[mi][ni] = zero4();

    #pragma unroll
    for (int ch = 0; ch < 6; ++ch) {
        bf16* xr = As + r * 136 + q * 32;
        if (ch < 4) {
            const float* sp = m + (size_t)(row0 + r) * 512 + ch * 128 + q * 32;
            #pragma unroll
            for (int i = 0; i < 8; ++i)
                *reinterpret_cast<ushort4*>(xr + i * 4) =
                    pack4(*reinterpret_cast<const float4*>(sp + i * 4));
        } else {
            const bf16* sp = hdst + (size_t)(row0 + r) * 256 + (ch - 4) * 128 + q * 32;
            #pragma unroll
            for (int i = 0; i < 8; ++i)
                *reinterpret_cast<ushort4*>(xr + i * 4) =
                    *reinterpret_cast<const ushort4*>(sp + i * 4);
        }
        __syncthreads();

        #pragma unroll
        for (int kk = 0; kk < 4; ++kk) {
            frag8 a[4], b[4];
            #pragma unroll
            for (int mi = 0; mi < 4; ++mi)
                a[mi] = *reinterpret_cast<const frag8*>(&As[(mi * 16 + lr) * 136 + kk * 32 + lk]);
            #pragma unroll
            for (int ni = 0; ni < 4; ++ni)
                b[ni] = *reinterpret_cast<const frag8*>(
                    WT + (size_t)(wave * 64 + ni * 16 + lr) * 768 + ch * 128 + kk * 32 + lk);
            #pragma unroll
            for (int mi = 0; mi < 4; ++mi)
                #pragma unroll
                for (int ni = 0; ni < 4; ++ni)
                    acc[mi][ni] = mfma16(a[mi], b[ni], acc[mi][ni]);
        }
        __syncthreads();
    }

    #pragma unroll
    for (int ni = 0; ni < 4; ++ni) {
        const int c = wave * 64 + ni * 16 + lr;
        const float bb = bias[c];
        #pragma unroll
        for (int mi = 0; mi < 4; ++mi)
            #pragma unroll
            for (int i = 0; i < 4; ++i)
                store_c(C + (size_t)(row0 + mi * 16 + lm4 + i) * 256 + c,
                        fmaxf(acc[mi][ni][i] + bb, 0.f));
    }
}

// ---------- l2 normalize rows of Z [rows,256] (bf16 in) -> bf16 out ----------
__global__ __launch_bounds__(256) void l2norm_kernel(
    const bf16* __restrict__ Z, bf16* __restrict__ out, int rows)
{
    const int wave = threadIdx.x >> 6, lane = threadIdx.x & 63;
    const int row = blockIdx.x * 4 + wave;
    if (row >= rows) return;
    const ushort4 u = *reinterpret_cast<const ushort4*>(Z + (size_t)row * 256 + lane * 4);
    float v[4] = { bfbits2f(u.x), bfbits2f(u.y), bfbits2f(u.z), bfbits2f(u.w) };
    float ss = v[0]*v[0] + v[1]*v[1] + v[2]*v[2] + v[3]*v[3];
    #pragma unroll
    for (int off = 32; off; off >>= 1) ss += __shfl_xor(ss, off, 64);
    const float scale = (ss == 0.f) ? 1.f : (1.f / sqrtf(ss));
    ushort4 o;
    o.x = f2bfbits(v[0]*scale); o.y = f2bfbits(v[1]*scale);
    o.z = f2bfbits(v[2]*scale); o.w = f2bfbits(v[3]*scale);
    *reinterpret_cast<ushort4*>(out + (size_t)row * 256 + lane * 4) = o;
}

// ---------- l2 normalize + skip add: out = P + Z/||Z|| (fp32) ----------
__global__ __launch_bounds__(256) void l2norm_add_kernel(
    const float* __restrict__ Z, const float* __restrict__ P,
    float* __restrict__ out, int rows)
{
    const int wave = threadIdx.x >> 6, lane = threadIdx.x & 63;
    const int row = blockIdx.x * 4 + wave;
    if (row >= rows) return;
    float v[4];
    load4f(Z + (size_t)row * 256 + lane * 4, v);
    float ss = v[0]*v[0] + v[1]*v[1] + v[2]*v[2] + v[3]*v[3];
    #pragma unroll
    for (int off = 32; off; off >>= 1) ss += __shfl_xor(ss, off, 64);
    const float scale = (ss == 0.f) ? 1.f : (1.f / sqrtf(ss));
    float p[4];
    load4f(P + (size_t)row * 256 + lane * 4, p);
    float4 o;
    o.x = p[0] + v[0]*scale; o.y = p[1] + v[1]*scale;
    o.z = p[2] + v[2]*scale; o.w = p[3] + v[3]*scale;
    *reinterpret_cast<float4*>(out + (size_t)row * 256 + lane * 4) = o;
}

// ---------- scoring: wave per edge; e<4096 -> pos, else neg. fp32 out ----------
__global__ __launch_bounds__(256) void score_kernel(
    const float* __restrict__ h,
    const int* __restrict__ ps, const int* __restrict__ pdi,
    const int* __restrict__ ns, const int* __restrict__ nd,
    const int* __restrict__ nid, const float* __restrict__ bias,
    float* __restrict__ out)
{
    const int wave = threadIdx.x >> 6, lane = threadIdx.x & 63;
    const int e = blockIdx.x * 4 + wave;
    const int ei = e & 4095;
    const int s = (e < 4096) ? ps[ei] : ns[ei];
    const int d = (e < 4096) ? pdi[ei] : nd[ei];
    float a[4], b[4];
    load4f(h + (size_t)s * 256 + lane * 4, a);
    load4f(h + (size_t)d * 256 + lane * 4, b);
    float dot = a[0]*b[0] + a[1]*b[1] + a[2]*b[2] + a[3]*b[3];
    #pragma unroll
    for (int off = 32; off; off >>= 1) dot += __shfl_xor(dot, off, 64);
    if (lane == 0)
        out[e] = dot + bias[nid[s]] + bias[nid[d]];
}

// ---------- launcher (R16-identical except edge kernel) ----------
extern "C" void kernel_launch(void* const* d_in, const int* in_sizes, int n_in,
                              void* d_out, int out_size, void* d_ws, size_t ws_size,
                              hipStream_t stream)
{
    const float* feat0    = (const float*)d_in[0];
    const float* feat_dst = (const float*)d_in[1];
    const float* weights0 = (const float*)d_in[2];
    const float* weights1 = (const float*)d_in[3];
    const float* W_proj   = (const float*)d_in[4];
    const float* b_proj   = (const float*)d_in[5];
    const float* Q1       = (const float*)d_in[6];
    const float* bq1      = (const float*)d_in[7];
    const float* W1       = (const float*)d_in[8];
    const float* bw1      = (const float*)d_in[9];
    const float* Q2       = (const float*)d_in[10];
    const float* bq2      = (const float*)d_in[11];
    const float* W2       = (const float*)d_in[12];
    const float* bw2      = (const float*)d_in[13];
    const float* biasN    = (const float*)d_in[14];
    const int* b0s = (const int*)d_in[15];
    const int* b0d = (const int*)d_in[16];
    const int* b1s = (const int*)d_in[17];
    const int* b1d = (const int*)d_in[18];
    const int* pos_src = (const int*)d_in[19];
    const int* pos_dst = (const int*)d_in[20];
    const int* neg_src = (const int*)d_in[21];
    const int* neg_dst = (const int*)d_in[22];
    const int* nid     = (const int*)d_in[23];

    // ---- workspace layout (~310 MiB, no aliasing; ws >= 513 MB proven) ----
    char* ws = (char*)d_ws;
    size_t off = 0;
    auto alloc = [&](size_t bytes) -> void* {
        void* p = ws + off; off += (bytes + 255) & ~(size_t)255; return p;
    };
    bf16*  h0     = (bf16*) alloc((size_t)N0c * 256 * 2);   // 169.87 MB
    float* m1     = (float*)alloc((size_t)N1c * 512 * 4);   //  75.50 MB
    bf16*  z1b    = (bf16*) alloc((size_t)N1c * 256 * 2);   //  18.87 MB
    bf16*  z1n    = (bf16*) alloc((size_t)N1c * 256 * 2);   //  18.87 MB
    float* m2     = (float*)alloc((size_t)N2c * 512 * 4);   //   8.39 MB
    float* z2     = (float*)alloc((size_t)N2c * 256 * 4);
    float* pdbuf  = (float*)alloc((size_t)N2c * 256 * 4);
    float* h_item = (float*)alloc((size_t)N2c * 256 * 4);
    bf16*  WpT    = (bf16*) alloc((size_t)256 * 128 * 2);
    bf16*  Q1T    = (bf16*) alloc((size_t)512 * 256 * 2);
    bf16*  Q2T    = (bf16*) alloc((size_t)512 * 256 * 2);
    bf16*  W1T    = (bf16*) alloc((size_t)256 * 768 * 2);
    bf16*  W2T    = (bf16*) alloc((size_t)256 * 768 * 2);
    int*   cnt    = (int*)  alloc((size_t)(N1c + 1) * 4);
    int*   base   = (int*)  alloc((size_t)(N1c + 1) * 4);
    int*   cursor = (int*)  alloc((size_t)N1c * 4);
    float* wsumf  = (float*)alloc((size_t)N1c * 4);
    float* invws  = (float*)alloc((size_t)N1c * 4);
    int*   perm   = (int*)  alloc((size_t)E0c * 4);

    // ---- prep: bf16 transposed weights ----
    transpose_bf16<<<(128*256 + 255)/256, 256, 0, stream>>>(W_proj, WpT, 128, 256);
    transpose_bf16<<<(256*512 + 255)/256, 256, 0, stream>>>(Q1, Q1T, 256, 512);
    transpose_bf16<<<(256*512 + 255)/256, 256, 0, stream>>>(Q2, Q2T, 256, 512);
    transpose_bf16<<<(768*256 + 255)/256, 256, 0, stream>>>(W1, W1T, 768, 256);
    transpose_bf16<<<(768*256 + 255)/256, 256, 0, stream>>>(W2, W2T, 768, 256);

    // ---- h0 = feat0 @ Wp + bp for ALL N0 nodes (bf16) ----
    gemm_mfma_proj<bf16><<<N0c/64, 256, 0, stream>>>(feat0, WpT, b_proj, h0);

    // ---- layer 1 CSR build ----
    hipMemsetAsync(cnt,    0, (size_t)N1c * 4, stream);
    hipMemsetAsync(cursor, 0, (size_t)N1c * 4, stream);
    hipMemsetAsync(wsumf,  0, (size_t)N1c * 4, stream);
    hist_kernel<<<E0c/256, 256, 0, stream>>>(b0d, weights0, cnt, wsumf, E0c);
    scan_kernel<<<1, 1024, 0, stream>>>(cnt, base, N1c);
    fill_kernel<<<E0c/256, 256, 0, stream>>>(b0d, base, cursor, perm, E0c);
    invws_kernel<<<(N1c + 255)/256, 256, 0, stream>>>(wsumf, invws, N1c);

    // ---- layer 1 fused wave-synchronous edge transform + reduce ----
    hipMemsetAsync(m1, 0, (size_t)N1c * 512 * 4, stream);
    edge_reduce_wave<<<E0c/64, 256, 0, stream>>>(
        h0, Q1T, bq1, perm, b0s, b0d, weights0, invws, m1);

    gemm_mfma_concat<bf16><<<N1c/64, 256, 0, stream>>>(m1, h0, W1T, bw1, z1b);
    l2norm_kernel<<<N1c/4, 256, 0, stream>>>(z1b, z1n, N1c);

    // ---- layer 2 CSR build ----
    hipMemsetAsync(cnt,    0, (size_t)N2c * 4, stream);
    hipMemsetAsync(cursor, 0, (size_t)N2c * 4, stream);
    hipMemsetAsync(wsumf,  0, (size_t)N2c * 4, stream);
    hist_kernel<<<E1c/256, 256, 0, stream>>>(b1d, weights1, cnt, wsumf, E1c);
    scan_kernel<<<1, 1024, 0, stream>>>(cnt, base, N2c);
    fill_kernel<<<E1c/256, 256, 0, stream>>>(b1d, base, cursor, perm, E1c);
    invws_kernel<<<(N2c + 255)/256, 256, 0, stream>>>(wsumf, invws, N2c);

    // ---- layer 2 fused wave-synchronous edge transform + reduce ----
    hipMemsetAsync(m2, 0, (size_t)N2c * 512 * 4, stream);
    edge_reduce_wave<<<E1c/64, 256, 0, stream>>>(
        z1n, Q2T, bq2, perm, b1s, b1d, weights1, invws, m2);

    gemm_mfma_concat<float><<<N2c/64, 256, 0, stream>>>(m2, z1n, W2T, bw2, z2);
    gemm_mfma_proj<float><<<N2c/64, 256, 0, stream>>>(feat_dst, WpT, b_proj, pdbuf);
    l2norm_add_kernel<<<N2c/4, 256, 0, stream>>>(z2, pdbuf, h_item, N2c);

    score_kernel<<<2048, 256, 0, stream>>>(
        h_item, pos_src, pos_dst, neg_src, neg_dst, nid, biasN, (float*)d_out);
}

// Round 18
// 689.340 us; speedup vs baseline: 1.4427x; 1.4427x over previous
//
#include <hip/hip_runtime.h>
#include <hip/hip_bf16.h>

typedef __hip_bfloat16 bf16;
typedef __attribute__((ext_vector_type(8))) short frag8;   // 8 bf16 = 4 VGPR (MFMA A/B)
typedef __attribute__((ext_vector_type(4))) float f32x4;   // MFMA C/D

#define N0c 331776
#define N1c 36864
#define N2c 4096
#define E0c 294912
#define E1c 32768

// ---------- helpers ----------
__device__ __forceinline__ float bfbits2f(unsigned short b) {
    union { unsigned u; float f; } x; x.u = ((unsigned)b) << 16; return x.f;
}
__device__ __forceinline__ float bfval2f(const bf16* p) {   // bit-correct bf16 -> f32
    return bfbits2f(*reinterpret_cast<const unsigned short*>(p));
}
__device__ __forceinline__ unsigned short f2bfbits(float f) {
    bf16 h = __float2bfloat16(f);
    return *reinterpret_cast<unsigned short*>(&h);
}
__device__ __forceinline__ void load4f(const float* p, float* o) {
    const float4 v = *reinterpret_cast<const float4*>(p);
    o[0] = v.x; o[1] = v.y; o[2] = v.z; o[3] = v.w;
}
__device__ __forceinline__ ushort4 pack4(float4 v) {
    ushort4 o; o.x = f2bfbits(v.x); o.y = f2bfbits(v.y);
    o.z = f2bfbits(v.z); o.w = f2bfbits(v.w); return o;
}
__device__ __forceinline__ void store_c(float* p, float v) { *p = v; }
__device__ __forceinline__ void store_c(bf16* p, float v)  { *p = __float2bfloat16(v); }
__device__ __forceinline__ f32x4 zero4() {
    f32x4 z; z[0] = 0.f; z[1] = 0.f; z[2] = 0.f; z[3] = 0.f; return z;
}
__device__ __forceinline__ f32x4 mfma16(frag8 a, frag8 b, f32x4 c) {
    return __builtin_amdgcn_mfma_f32_16x16x32_bf16(a, b, c, 0, 0, 0);
}

// ---------- prep: fp32 [K][N] -> bf16 transposed [N][K] ----------
__global__ __launch_bounds__(256) void transpose_bf16(
    const float* __restrict__ src, bf16* __restrict__ dst, int K, int N)
{
    const int idx = blockIdx.x * 256 + threadIdx.x;
    if (idx >= K * N) return;
    const int k = idx / N, n = idx - k * N;
    dst[(size_t)n * K + k] = __float2bfloat16(src[idx]);
}

// ---------- CSR build ----------
__global__ __launch_bounds__(256) void hist_kernel(
    const int* __restrict__ dst, const float* __restrict__ w,
    int* __restrict__ cnt, float* __restrict__ wsum, int E)
{
    const int e = blockIdx.x * 256 + threadIdx.x;
    if (e < E) {
        const int d = dst[e];
        atomicAdd(&cnt[d], 1);
        atomicAdd(&wsum[d], w[e]);
    }
}

__global__ __launch_bounds__(256) void invws_kernel(
    const float* __restrict__ wsum, float* __restrict__ invws, int n)
{
    const int i = blockIdx.x * 256 + threadIdx.x;
    if (i < n) invws[i] = 1.f / fmaxf(wsum[i], 1.f);
}

// n multiple of 4096 (chunk stays multiple of 4 for int4 loads)
__global__ __launch_bounds__(1024) void scan_kernel(
    const int* __restrict__ cnt, int* __restrict__ base, int n)
{
    __shared__ int ps[1024];
    const int t = threadIdx.x;
    const int chunk = (n + 1023) >> 10;
    const int lo = t * chunk;
    const int hi = (lo + chunk < n) ? lo + chunk : n;
    int s = 0;
    for (int i = lo; i < hi; i += 4) {
        const int4 v = *reinterpret_cast<const int4*>(cnt + i);
        s += v.x + v.y + v.z + v.w;
    }
    ps[t] = s;
    __syncthreads();
    for (int off = 1; off < 1024; off <<= 1) {
        int v = (t >= off) ? ps[t - off] : 0;
        __syncthreads();
        ps[t] += v;
        __syncthreads();
    }
    int run = ps[t] - s;
    for (int i = lo; i < hi; ++i) { base[i] = run; run += cnt[i]; }
    if (t == 1023) base[n] = ps[1023];
}

__global__ __launch_bounds__(256) void fill_kernel(
    const int* __restrict__ dst, const int* __restrict__ base,
    int* __restrict__ cursor, int* __restrict__ perm, int E)
{
    const int e = blockIdx.x * 256 + threadIdx.x;
    if (e < E) {
        const int d = dst[e];
        const int p = base[d] + atomicAdd(&cursor[d], 1);
        perm[p] = e;
    }
}

// ---------- MFMA proj GEMM: C[M,256] = A[M,128] @ Wp + bp (R7-proven) ----------
template<typename TC>
__global__ __launch_bounds__(256) void gemm_mfma_proj(
    const float* __restrict__ A, const bf16* __restrict__ WpT,
    const float* __restrict__ bp, TC* __restrict__ C)
{
    __shared__ bf16 Xs[64 * 136];

    const int tid = threadIdx.x;
    const int lane = tid & 63, wave = tid >> 6;
    const int row0 = blockIdx.x * 64;

    {   // stage A rows -> bf16 LDS
        const int r = tid >> 2, q = tid & 3;
        const float* ar = A + (size_t)(row0 + r) * 128 + q * 32;
        bf16* xr = Xs + r * 136 + q * 32;
        #pragma unroll
        for (int i = 0; i < 8; ++i)
            *reinterpret_cast<ushort4*>(xr + i * 4) =
                pack4(*reinterpret_cast<const float4*>(ar + i * 4));
    }
    __syncthreads();

    const int lr = lane & 15;
    const int lk = (lane >> 4) * 8;
    const int lm4 = (lane >> 4) * 4;

    f32x4 acc[4][4];
    #pragma unroll
    for (int mi = 0; mi < 4; ++mi)
        #pragma unroll
        for (int ni = 0; ni < 4; ++ni) acc[mi][ni] = zero4();

    #pragma unroll
    for (int kk = 0; kk < 4; ++kk) {
        frag8 a[4], b[4];
        #pragma unroll
        for (int mi = 0; mi < 4; ++mi)
            a[mi] = *reinterpret_cast<const frag8*>(&Xs[(mi * 16 + lr) * 136 + kk * 32 + lk]);
        #pragma unroll
        for (int ni = 0; ni < 4; ++ni)
            b[ni] = *reinterpret_cast<const frag8*>(
                WpT + (size_t)(wave * 64 + ni * 16 + lr) * 128 + kk * 32 + lk);
        #pragma unroll
        for (int mi = 0; mi < 4; ++mi)
            #pragma unroll
            for (int ni = 0; ni < 4; ++ni)
                acc[mi][ni] = mfma16(a[mi], b[ni], acc[mi][ni]);
    }

    #pragma unroll
    for (int ni = 0; ni < 4; ++ni) {
        const int c = wave * 64 + ni * 16 + lr;
        const float bb = bp[c];
        #pragma unroll
        for (int mi = 0; mi < 4; ++mi)
            #pragma unroll
            for (int i = 0; i < 4; ++i)
                store_c(C + (size_t)(row0 + mi * 16 + lm4 + i) * 256 + c,
                        acc[mi][ni][i] + bb);
    }
}

// ---------- fused edge transform + segment reduce (CSR order), 64 rows/block ----------
// R12/R16-proven structure (best of 17 rounds). m[d] += relu(z[src]@Q+bq)*w * invws[d].
// All flushes atomicAdd onto zero-init m (order-independent, race-free).
__global__ __launch_bounds__(256) void edge_reduce_csr(
    const bf16* __restrict__ zn, const bf16* __restrict__ QT,
    const float* __restrict__ bq,
    const int* __restrict__ perm, const int* __restrict__ srcv,
    const int* __restrict__ dstv, const float* __restrict__ w,
    const float* __restrict__ invws, float* __restrict__ mout)
{
    __shared__ bf16 Zs[64 * 264];    // 33.8 KB gathered input
    __shared__ bf16 Os[64 * 264];    // 33.8 KB staged weighted outputs
    __shared__ int   srcs[64];
    __shared__ int   dsts[64];
    __shared__ float wts[64];

    const int tid = threadIdx.x;
    const int lane = tid & 63, wave = tid >> 6;
    const size_t p0 = (size_t)blockIdx.x * 64;

    if (tid < 64) {
        const int e = perm[p0 + tid];
        srcs[tid] = srcv[e];
        dsts[tid] = dstv[e];
        wts[tid]  = w[e];
    }
    __syncthreads();

    {   // gather 64 rows x 256 bf16; thread -> (row r, quarter q), 8x16B loads
        const int r = tid >> 2, q = tid & 3;
        const int4* zr = reinterpret_cast<const int4*>(
            zn + (size_t)srcs[r] * 256 + q * 64);
        int4* zo = reinterpret_cast<int4*>(Zs + r * 264 + q * 64);
        #pragma unroll
        for (int i = 0; i < 8; ++i) zo[i] = zr[i];
    }
    __syncthreads();

    const int lr = lane & 15;
    const int lk = (lane >> 4) * 8;
    const int lm4 = (lane >> 4) * 4;

    for (int pass = 0; pass < 2; ++pass) {
        const int nc0 = wave * 128 + pass * 64;
        f32x4 acc[4][4];
        #pragma unroll
        for (int mi = 0; mi < 4; ++mi)
            #pragma unroll
            for (int ni = 0; ni < 4; ++ni) acc[mi][ni] = zero4();

        #pragma unroll
        for (int kk = 0; kk < 8; ++kk) {
            frag8 a[4], b[4];
            #pragma unroll
            for (int mi = 0; mi < 4; ++mi)
                a[mi] = *reinterpret_cast<const frag8*>(&Zs[(mi * 16 + lr) * 264 + kk * 32 + lk]);
            #pragma unroll
            for (int ni = 0; ni < 4; ++ni)
                b[ni] = *reinterpret_cast<const frag8*>(
                    QT + (size_t)(nc0 + ni * 16 + lr) * 256 + kk * 32 + lk);
            #pragma unroll
            for (int mi = 0; mi < 4; ++mi)
                #pragma unroll
                for (int ni = 0; ni < 4; ++ni)
                    acc[mi][ni] = mfma16(a[mi], b[ni], acc[mi][ni]);
        }

        // epilogue: relu+bias, weight by w[row], stage to Os
        // local col lc = wave*64+ni*16+lr  <->  global col gc = wave*128+pass*64+ni*16+lr
        #pragma unroll
        for (int ni = 0; ni < 4; ++ni) {
            const int gc = nc0 + ni * 16 + lr;
            const float bb = bq[gc];
            const int lc = wave * 64 + ni * 16 + lr;
            #pragma unroll
            for (int mi = 0; mi < 4; ++mi)
                #pragma unroll
                for (int i = 0; i < 4; ++i) {
                    const int row = mi * 16 + lm4 + i;
                    const float val = fmaxf(acc[mi][ni][i] + bb, 0.f) * wts[row];
                    Os[row * 264 + lc] = __float2bfloat16(val);
                }
        }
        __syncthreads();

        // segment reduce: thread owns one local column; scan the 64 CSR-sorted rows
        {
            const int L = tid;
            const int gc = (L >> 6) * 128 + pass * 64 + (L & 63);
            float a = 0.f;
            int cur = dsts[0];
            for (int r = 0; r < 64; ++r) {
                const int d = dsts[r];
                if (d != cur) {
                    atomicAdd(&mout[(size_t)cur * 512 + gc], a * invws[cur]);
                    a = 0.f; cur = d;
                }
                a += bfval2f(&Os[r * 264 + L]);   // bit-reinterpret read (R12 fix)
            }
            atomicAdd(&mout[(size_t)cur * 512 + gc], a * invws[cur]);
        }
        __syncthreads();
    }
}

// ---------- MFMA concat GEMM: C[M,256] = relu([m_f32 | hdst] @ W + bias) ----------
template<typename TC>
__global__ __launch_bounds__(256) void gemm_mfma_concat(
    const float* __restrict__ m, const bf16* __restrict__ hdst,
    const bf16* __restrict__ WT, const float* __restrict__ bias,
    TC* __restrict__ C)
{
    __shared__ bf16 As[64 * 136];

    const int tid = threadIdx.x;
    const int lane = tid & 63, wave = tid >> 6;
    const int row0 = blockIdx.x * 64;
    const int r = tid >> 2, q = tid & 3;

    const int lr = lane & 15;
    const int lk = (lane >> 4) * 8;
    const int lm4 = (lane >> 4) * 4;

    f32x4 acc[4][4];
    #pragma unroll
    for (int mi = 0; mi < 4; ++mi)
        #pragma unroll
        for (int ni = 0; ni < 4; ++ni) acc[mi][ni] = zero4();

    #pragma unroll
    for (int ch = 0; ch < 6; ++ch) {
        bf16* xr = As + r * 136 + q * 32;
        if (ch < 4) {
            const float* sp = m + (size_t)(row0 + r) * 512 + ch * 128 + q * 32;
            #pragma unroll
            for (int i = 0; i < 8; ++i)
                *reinterpret_cast<ushort4*>(xr + i * 4) =
                    pack4(*reinterpret_cast<const float4*>(sp + i * 4));
        } else {
            const bf16* sp = hdst + (size_t)(row0 + r) * 256 + (ch - 4) * 128 + q * 32;
            #pragma unroll
            for (int i = 0; i < 8; ++i)
                *reinterpret_cast<ushort4*>(xr + i * 4) =
                    *reinterpret_cast<const ushort4*>(sp + i * 4);
        }
        __syncthreads();

        #pragma unroll
        for (int kk = 0; kk < 4; ++kk) {
            frag8 a[4], b[4];
            #pragma unroll
            for (int mi = 0; mi < 4; ++mi)
                a[mi] = *reinterpret_cast<const frag8*>(&As[(mi * 16 + lr) * 136 + kk * 32 + lk]);
            #pragma unroll
            for (int ni = 0; ni < 4; ++ni)
                b[ni] = *reinterpret_cast<const frag8*>(
                    WT + (size_t)(wave * 64 + ni * 16 + lr) * 768 + ch * 128 + kk * 32 + lk);
            #pragma unroll
            for (int mi = 0; mi < 4; ++mi)
                #pragma unroll
                for (int ni = 0; ni < 4; ++ni)
                    acc[mi][ni] = mfma16(a[mi], b[ni], acc[mi][ni]);
        }
        __syncthreads();
    }

    #pragma unroll
    for (int ni = 0; ni < 4; ++ni) {
        const int c = wave * 64 + ni * 16 + lr;
        const float bb = bias[c];
        #pragma unroll
        for (int mi = 0; mi < 4; ++mi)
            #pragma unroll
            for (int i = 0; i < 4; ++i)
                store_c(C + (size_t)(row0 + mi * 16 + lm4 + i) * 256 + c,
                        fmaxf(acc[mi][ni][i] + bb, 0.f));
    }
}

// ---------- l2 normalize rows of Z [rows,256] (bf16 in) -> bf16 out ----------
__global__ __launch_bounds__(256) void l2norm_kernel(
    const bf16* __restrict__ Z, bf16* __restrict__ out, int rows)
{
    const int wave = threadIdx.x >> 6, lane = threadIdx.x & 63;
    const int row = blockIdx.x * 4 + wave;
    if (row >= rows) return;
    const ushort4 u = *reinterpret_cast<const ushort4*>(Z + (size_t)row * 256 + lane * 4);
    float v[4] = { bfbits2f(u.x), bfbits2f(u.y), bfbits2f(u.z), bfbits2f(u.w) };
    float ss = v[0]*v[0] + v[1]*v[1] + v[2]*v[2] + v[3]*v[3];
    #pragma unroll
    for (int off = 32; off; off >>= 1) ss += __shfl_xor(ss, off, 64);
    const float scale = (ss == 0.f) ? 1.f : (1.f / sqrtf(ss));
    ushort4 o;
    o.x = f2bfbits(v[0]*scale); o.y = f2bfbits(v[1]*scale);
    o.z = f2bfbits(v[2]*scale); o.w = f2bfbits(v[3]*scale);
    *reinterpret_cast<ushort4*>(out + (size_t)row * 256 + lane * 4) = o;
}

// ---------- l2 normalize + skip add: out = P + Z/||Z|| (fp32) ----------
__global__ __launch_bounds__(256) void l2norm_add_kernel(
    const float* __restrict__ Z, const float* __restrict__ P,
    float* __restrict__ out, int rows)
{
    const int wave = threadIdx.x >> 6, lane = threadIdx.x & 63;
    const int row = blockIdx.x * 4 + wave;
    if (row >= rows) return;
    float v[4];
    load4f(Z + (size_t)row * 256 + lane * 4, v);
    float ss = v[0]*v[0] + v[1]*v[1] + v[2]*v[2] + v[3]*v[3];
    #pragma unroll
    for (int off = 32; off; off >>= 1) ss += __shfl_xor(ss, off, 64);
    const float scale = (ss == 0.f) ? 1.f : (1.f / sqrtf(ss));
    float p[4];
    load4f(P + (size_t)row * 256 + lane * 4, p);
    float4 o;
    o.x = p[0] + v[0]*scale; o.y = p[1] + v[1]*scale;
    o.z = p[2] + v[2]*scale; o.w = p[3] + v[3]*scale;
    *reinterpret_cast<float4*>(out + (size_t)row * 256 + lane * 4) = o;
}

// ---------- scoring: wave per edge; e<4096 -> pos, else neg. fp32 out ----------
__global__ __launch_bounds__(256) void score_kernel(
    const float* __restrict__ h,
    const int* __restrict__ ps, const int* __restrict__ pdi,
    const int* __restrict__ ns, const int* __restrict__ nd,
    const int* __restrict__ nid, const float* __restrict__ bias,
    float* __restrict__ out)
{
    const int wave = threadIdx.x >> 6, lane = threadIdx.x & 63;
    const int e = blockIdx.x * 4 + wave;
    const int ei = e & 4095;
    const int s = (e < 4096) ? ps[ei] : ns[ei];
    const int d = (e < 4096) ? pdi[ei] : nd[ei];
    float a[4], b[4];
    load4f(h + (size_t)s * 256 + lane * 4, a);
    load4f(h + (size_t)d * 256 + lane * 4, b);
    float dot = a[0]*b[0] + a[1]*b[1] + a[2]*b[2] + a[3]*b[3];
    #pragma unroll
    for (int off = 32; off; off >>= 1) dot += __shfl_xor(dot, off, 64);
    if (lane == 0)
        out[e] = dot + bias[nid[s]] + bias[nid[d]];
}

// ---------- launcher (R16-identical) ----------
extern "C" void kernel_launch(void* const* d_in, const int* in_sizes, int n_in,
                              void* d_out, int out_size, void* d_ws, size_t ws_size,
                              hipStream_t stream)
{
    const float* feat0    = (const float*)d_in[0];
    const float* feat_dst = (const float*)d_in[1];
    const float* weights0 = (const float*)d_in[2];
    const float* weights1 = (const float*)d_in[3];
    const float* W_proj   = (const float*)d_in[4];
    const float* b_proj   = (const float*)d_in[5];
    const float* Q1       = (const float*)d_in[6];
    const float* bq1      = (const float*)d_in[7];
    const float* W1       = (const float*)d_in[8];
    const float* bw1      = (const float*)d_in[9];
    const float* Q2       = (const float*)d_in[10];
    const float* bq2      = (const float*)d_in[11];
    const float* W2       = (const float*)d_in[12];
    const float* bw2      = (const float*)d_in[13];
    const float* biasN    = (const float*)d_in[14];
    const int* b0s = (const int*)d_in[15];
    const int* b0d = (const int*)d_in[16];
    const int* b1s = (const int*)d_in[17];
    const int* b1d = (const int*)d_in[18];
    const int* pos_src = (const int*)d_in[19];
    const int* pos_dst = (const int*)d_in[20];
    const int* neg_src = (const int*)d_in[21];
    const int* neg_dst = (const int*)d_in[22];
    const int* nid     = (const int*)d_in[23];

    // ---- workspace layout (~310 MiB, no aliasing; ws >= 513 MB proven) ----
    char* ws = (char*)d_ws;
    size_t off = 0;
    auto alloc = [&](size_t bytes) -> void* {
        void* p = ws + off; off += (bytes + 255) & ~(size_t)255; return p;
    };
    bf16*  h0     = (bf16*) alloc((size_t)N0c * 256 * 2);   // 169.87 MB
    float* m1     = (float*)alloc((size_t)N1c * 512 * 4);   //  75.50 MB
    bf16*  z1b    = (bf16*) alloc((size_t)N1c * 256 * 2);   //  18.87 MB
    bf16*  z1n    = (bf16*) alloc((size_t)N1c * 256 * 2);   //  18.87 MB
    float* m2     = (float*)alloc((size_t)N2c * 512 * 4);   //   8.39 MB
    float* z2     = (float*)alloc((size_t)N2c * 256 * 4);
    float* pdbuf  = (float*)alloc((size_t)N2c * 256 * 4);
    float* h_item = (float*)alloc((size_t)N2c * 256 * 4);
    bf16*  WpT    = (bf16*) alloc((size_t)256 * 128 * 2);
    bf16*  Q1T    = (bf16*) alloc((size_t)512 * 256 * 2);
    bf16*  Q2T    = (bf16*) alloc((size_t)512 * 256 * 2);
    bf16*  W1T    = (bf16*) alloc((size_t)256 * 768 * 2);
    bf16*  W2T    = (bf16*) alloc((size_t)256 * 768 * 2);
    int*   cnt    = (int*)  alloc((size_t)(N1c + 1) * 4);
    int*   base   = (int*)  alloc((size_t)(N1c + 1) * 4);
    int*   cursor = (int*)  alloc((size_t)N1c * 4);
    float* wsumf  = (float*)alloc((size_t)N1c * 4);
    float* invws  = (float*)alloc((size_t)N1c * 4);
    int*   perm   = (int*)  alloc((size_t)E0c * 4);

    // ---- prep: bf16 transposed weights ----
    transpose_bf16<<<(128*256 + 255)/256, 256, 0, stream>>>(W_proj, WpT, 128, 256);
    transpose_bf16<<<(256*512 + 255)/256, 256, 0, stream>>>(Q1, Q1T, 256, 512);
    transpose_bf16<<<(256*512 + 255)/256, 256, 0, stream>>>(Q2, Q2T, 256, 512);
    transpose_bf16<<<(768*256 + 255)/256, 256, 0, stream>>>(W1, W1T, 768, 256);
    transpose_bf16<<<(768*256 + 255)/256, 256, 0, stream>>>(W2, W2T, 768, 256);

    // ---- h0 = feat0 @ Wp + bp for ALL N0 nodes (bf16) ----
    gemm_mfma_proj<bf16><<<N0c/64, 256, 0, stream>>>(feat0, WpT, b_proj, h0);

    // ---- layer 1 CSR build ----
    hipMemsetAsync(cnt,    0, (size_t)N1c * 4, stream);
    hipMemsetAsync(cursor, 0, (size_t)N1c * 4, stream);
    hipMemsetAsync(wsumf,  0, (size_t)N1c * 4, stream);
    hist_kernel<<<E0c/256, 256, 0, stream>>>(b0d, weights0, cnt, wsumf, E0c);
    scan_kernel<<<1, 1024, 0, stream>>>(cnt, base, N1c);
    fill_kernel<<<E0c/256, 256, 0, stream>>>(b0d, base, cursor, perm, E0c);
    invws_kernel<<<(N1c + 255)/256, 256, 0, stream>>>(wsumf, invws, N1c);

    // ---- layer 1 fused edge transform + reduce (64 rows/block) ----
    hipMemsetAsync(m1, 0, (size_t)N1c * 512 * 4, stream);
    edge_reduce_csr<<<E0c/64, 256, 0, stream>>>(
        h0, Q1T, bq1, perm, b0s, b0d, weights0, invws, m1);

    gemm_mfma_concat<bf16><<<N1c/64, 256, 0, stream>>>(m1, h0, W1T, bw1, z1b);
    l2norm_kernel<<<N1c/4, 256, 0, stream>>>(z1b, z1n, N1c);

    // ---- layer 2 CSR build ----
    hipMemsetAsync(cnt,    0, (size_t)N2c * 4, stream);
    hipMemsetAsync(cursor, 0, (size_t)N2c * 4, stream);
    hipMemsetAsync(wsumf,  0, (size_t)N2c * 4, stream);
    hist_kernel<<<E1c/256, 256, 0, stream>>>(b1d, weights1, cnt, wsumf, E1c);
    scan_kernel<<<1, 1024, 0, stream>>>(cnt, base, N2c);
    fill_kernel<<<E1c/256, 256, 0, stream>>>(b1d, base, cursor, perm, E1c);
    invws_kernel<<<(N2c + 255)/256, 256, 0, stream>>>(wsumf, invws, N2c);

    // ---- layer 2 fused edge transform + reduce ----
    hipMemsetAsync(m2, 0, (size_t)N2c * 512 * 4, stream);
    edge_reduce_csr<<<E1c/64, 256, 0, stream>>>(
        z1n, Q2T, bq2, perm, b1s, b1d, weights1, invws, m2);

    gemm_mfma_concat<float><<<N2c/64, 256, 0, stream>>>(m2, z1n, W2T, bw2, z2);
    gemm_mfma_proj<float><<<N2c/64, 256, 0, stream>>>(feat_dst, WpT, b_proj, pdbuf);
    l2norm_add_kernel<<<N2c/4, 256, 0, stream>>>(z2, pdbuf, h_item, N2c);

    score_kernel<<<2048, 256, 0, stream>>>(
        h_item, pos_src, pos_dst, neg_src, neg_dst, nid, biasN, (float*)d_out);
}